// Round 10
// baseline (330.833 us; speedup 1.0000x reference)
//
#include <hip/hip_runtime.h>
#include <hip/hip_bf16.h>

typedef unsigned short u16;
typedef __attribute__((ext_vector_type(8))) short short8;
typedef __attribute__((ext_vector_type(4))) float f32x4;
typedef __attribute__((ext_vector_type(2))) float f32x2;
typedef __attribute__((ext_vector_type(16))) float f32x16;

#define MFMA16(a, b, c) __builtin_amdgcn_mfma_f32_16x16x32_bf16((a), (b), (c), 0, 0, 0)
#define MFMA32(a, b, c) __builtin_amdgcn_mfma_f32_32x32x16_bf16((a), (b), (c), 0, 0, 0)

__device__ __forceinline__ u16 f2bf(float f) {
  __hip_bfloat16 h = __float2bfloat16(f);
  u16 r;
  __builtin_memcpy(&r, &h, 2);
  return r;
}
__device__ __forceinline__ float bf2f(u16 h) {
  unsigned u = ((unsigned)h) << 16;
  float f;
  __builtin_memcpy(&f, &u, 4);
  return f;
}
// Single-instruction packed f32x2 -> bf16x2 (gfx950 v_cvt_pk_bf16_f32, RNE).
__device__ __forceinline__ unsigned pk2(float a, float b) {
  unsigned r;
  asm("v_cvt_pk_bf16_f32 %0, %1, %2" : "=v"(r) : "v"(a), "v"(b));
  return r;
}
// Load 8 consecutive source elements as bf16 short8 from f32 or bf16 storage.
__device__ __forceinline__ short8 ld8(const void* src, int idx, int isf32) {
  short8 v;
  if (isf32) {
    const float4* s = (const float4*)((const float*)src + idx);
    float4 p0 = s[0], p1 = s[1];
    unsigned d0 = pk2(p0.x, p0.y), d1 = pk2(p0.z, p0.w);
    unsigned d2 = pk2(p1.x, p1.y), d3 = pk2(p1.z, p1.w);
    uint4 dd = {d0, d1, d2, d3};
    __builtin_memcpy(&v, &dd, 16);
  } else {
    v = *(const short8*)((const u16*)src + idx);
  }
  return v;
}
__device__ __forceinline__ float ld1(const void* src, int idx, int isf32) {
  return isf32 ? ((const float*)src)[idx] : bf2f(((const u16*)src)[idx]);
}
// Per-block input-dtype detect (wave-uniform; f32 halves have hot exponents).
__device__ __forceinline__ int detect_isf32(const u16* xw) {
  int lane = threadIdx.x & 63;
  int cnt = 0;
#pragma unroll
  for (int i = 0; i < 16; ++i) {
    u16 w = xw[lane * 16 + i];
    cnt += (((w >> 7) & 0xFF) >= 0xC0) ? 1 : 0;
  }
#pragma unroll
  for (int off = 1; off < 64; off <<= 1) cnt += __shfl_xor(cnt, off, 64);
  return cnt >= 32;
}

// ---------------------------------------------------------------------------
// ws layout (u16 elements):
//   WcT [16][128cout][128cin]  @ 0
//   WqT/WkT/WvT/WpT [128][128] @ 262144/278528/294912/311296
//   Kb  [4][1024][128]         @ 327680
//   Vt  [4][128][1024]         @ 851968
// ---------------------------------------------------------------------------
// Re-enumerated so the f32 READ side is coalesced (gid == src index, 4-B
// stride); the cheap 2-B writes take the scatter instead (stores don't stall).
__global__ void prep_kernel(const void* __restrict__ srk, const void* __restrict__ Wq,
                            const void* __restrict__ Wk, const void* __restrict__ Wv,
                            const void* __restrict__ Wp, const void* __restrict__ x,
                            u16* __restrict__ WcT) {
  const int isf32 = detect_isf32((const u16*)x);
  int gid = blockIdx.x * 256 + threadIdx.x;
  if (gid >= 327680) return;
  float v;
  int dst;
  if (gid < 262144) {
    int mat = gid >> 14, cin = (gid >> 7) & 127, cout = gid & 127;
    v = ld1(srk, gid, isf32);  // mat*16384 + cin*128 + cout == gid (coalesced)
    dst = mat * 16384 + cout * 128 + cin;
  } else {
    int g2 = gid - 262144;
    int mat = g2 >> 14, cin = (g2 >> 7) & 127, cout = g2 & 127;
    const void* src = (mat == 0) ? Wq : (mat == 1) ? Wk : (mat == 2) ? Wv : Wp;
    v = ld1(src, cin * 128 + cout, isf32);  // == g2 & 16383 (coalesced)
    dst = 262144 + mat * 16384 + cout * 128 + cin;
  }
  WcT[dst] = f2bf(v);
}

// ---------------------------------------------------------------------------
// Conv (stride-4 4x4 'SAME' == patch GEMM) + bias + LayerNorm + fused K/V.
// Grid 256 WGs x 1024 thr (16 waves). Wave w owns conv tap rs=w (K-split 16).
// Vt store packed (one 8-B uint2 per lane). Unchanged from round 9.
// ---------------------------------------------------------------------------
__launch_bounds__(1024, 4)
__global__ void conv_ln_kv_kernel(const void* __restrict__ x, const u16* __restrict__ wcT,
                                  const void* __restrict__ sr_bias,
                                  const void* __restrict__ gamma,
                                  const void* __restrict__ beta,
                                  const u16* __restrict__ WkT, const u16* __restrict__ WvT,
                                  u16* __restrict__ Kb, u16* __restrict__ Vt) {
  extern __shared__ char cws[];
  float* Racc = (float*)cws;                    // [16][16][128] f32 = 128 KB
  u16* Xs = (u16*)(cws + 16 * 16 * 128 * 4);    // [16][136] bf16
  const int isf32 = detect_isf32((const u16*)x);
  const int tid = threadIdx.x;
  const int wave = tid >> 6, lane = tid & 63;
  const int quad = lane >> 4, l16 = lane & 15;
  const int g = blockIdx.x;  // rows g*16 .. g*16+15

  const int row = g * 16 + l16;
  const int pb = row >> 10, rem = row & 1023, oh = rem >> 5, ow = rem & 31;
  const int xbase = ((pb * 128 + oh * 4) * 128 + ow * 4) * 128;

  f32x4 acc[8];
#pragma unroll
  for (int i = 0; i < 8; ++i) acc[i] = (f32x4){0.f, 0.f, 0.f, 0.f};

  {  // tap rs = wave (r = wave>>2, s = wave&3)
    const int r = wave >> 2, sc = wave & 3;
    short8 a[4];
#pragma unroll
    for (int kc = 0; kc < 4; ++kc)
      a[kc] = ld8(x, xbase + r * 16384 + sc * 128 + kc * 32 + quad * 8, isf32);
#pragma unroll
    for (int nt = 0; nt < 8; ++nt)
#pragma unroll
      for (int kc = 0; kc < 4; ++kc) {
        short8 bw = *(const short8*)(wcT + wave * 16384 + (nt * 16 + l16) * 128 +
                                     kc * 32 + quad * 8);
        acc[nt] = MFMA16(a[kc], bw, acc[nt]);
      }
  }
  // partials -> LDS
#pragma unroll
  for (int nt = 0; nt < 8; ++nt)
#pragma unroll
    for (int rr = 0; rr < 4; ++rr)
      Racc[(wave * 16 + quad * 4 + rr) * 128 + nt * 16 + l16] = acc[nt][rr];
  __syncthreads();

  // reduce 16 wave-slices; wave owns row `wave`, lane owns 2 cols at lane*2
  {
    const int lrow = wave, c0 = lane * 2;
    f32x2 rsum = (f32x2){0.f, 0.f};
#pragma unroll
    for (int w = 0; w < 16; ++w) {
      f32x2 t = *(const f32x2*)&Racc[(w * 16 + lrow) * 128 + c0];
      rsum[0] += t[0];
      rsum[1] += t[1];
    }
    float v0 = rsum[0] + ld1(sr_bias, c0, isf32);
    float v1 = rsum[1] + ld1(sr_bias, c0 + 1, isf32);
    float sum = v0 + v1, sum2 = v0 * v0 + v1 * v1;
#pragma unroll
    for (int off = 1; off < 64; off <<= 1) {
      sum += __shfl_xor(sum, off, 64);
      sum2 += __shfl_xor(sum2, off, 64);
    }
    const float mu = sum * (1.f / 128.f);
    const float var = sum2 * (1.f / 128.f) - mu * mu;
    const float rinv = rsqrtf(fmaxf(var, 0.f) + 1e-6f);
    float y0 = (v0 - mu) * rinv * ld1(gamma, c0, isf32) + ld1(beta, c0, isf32);
    float y1 = (v1 - mu) * rinv * ld1(gamma, c0 + 1, isf32) + ld1(beta, c0 + 1, isf32);
    *(unsigned*)&Xs[lrow * 136 + c0] = pk2(y0, y1);
  }
  __syncthreads();

  // fused K/V projection: wave w -> nt = w>>1; even waves K, odd waves V
  short8 a2[4];
#pragma unroll
  for (int kc = 0; kc < 4; ++kc)
    a2[kc] = *(const short8*)&Xs[l16 * 136 + kc * 32 + quad * 8];
  const u16* Wm = (wave & 1) ? WvT : WkT;
  const int nt = wave >> 1;
  f32x4 a3 = (f32x4){0.f, 0.f, 0.f, 0.f};
#pragma unroll
  for (int kc = 0; kc < 4; ++kc) {
    short8 bm = *(const short8*)(Wm + (nt * 16 + l16) * 128 + kc * 32 + quad * 8);
    a3 = MFMA16(a2[kc], bm, a3);
  }
  const int rowg0 = g * 16 + quad * 4;            // 4-aligned; never crosses 1024
  const int b0 = rowg0 >> 10, key0 = rowg0 & 1023;
  const int c = nt * 16 + l16;
  if (wave & 1) {
    uint2 pv = {pk2(a3[0], a3[1]), pk2(a3[2], a3[3])};
    *(uint2*)&Vt[(b0 * 128 + c) * 1024 + key0] = pv;  // 8-B aligned packed store
  } else {
#pragma unroll
    for (int rr = 0; rr < 4; ++rr) Kb[(rowg0 + rr) * 128 + c] = f2bf(a3[rr]);
  }
}

// ---------------------------------------------------------------------------
// Fused attention, 32x32x16 MFMA core. Grid 512 x 256 thr (4 waves x 32 q).
// ONLY change vs round 9: __launch_bounds__(256, 3) -> 3 WGs/CU.
//   - LDS 54272 B x 3 = 162816 <= 163840  (fits)
//   - VGPR cap 512/3 = 170 > measured 120 (no re-allocation, no spill risk;
//     round-7's spill was cap 128 < live ~150 — here the binary already
//     fits the cap with 50 regs of slack)
// Round-1 precedent: 1->2 WGs/CU was 150->116 us; the kernel is barrier-
// phase-locked so cross-WG overlap is the only latency cover available.
// Layouts verified by rounds 7/8/9 passing.
// ---------------------------------------------------------------------------
__launch_bounds__(256, 3)
__global__ void attn_kernel(const void* __restrict__ x, const u16* __restrict__ WqT,
                            const u16* __restrict__ WpT, const u16* __restrict__ Kb,
                            const u16* __restrict__ Vt, float* __restrict__ out) {
  extern __shared__ u16 lds[];
  u16* Ks = lds;             // [64][136]  8704 el
  u16* Vs = Ks + 64 * 136;   // [128][72]  9216 el
  u16* Pp = Vs + 128 * 72;   // [4][2304]  per-wave P scratch [32][72]
  const int isf32 = detect_isf32((const u16*)x);
  const int tid = threadIdx.x;
  const int wave = tid >> 6, lane = tid & 63;
  const int quad = lane >> 4, l16 = lane & 15;   // 16x16 frag indexing
  const int q32 = lane & 31, hi = lane >> 5;     // 32x32 frag indexing
  const int swz = (blockIdx.x & 7) * 64 + (blockIdx.x >> 3);  // XCD-contiguous
  const int b = swz >> 7;
  const int row0 = (swz & 127) * 128;
  const int wrow = wave * 32;
  u16* Pw = Pp + wave * 2304;   // in-loop P scratch [32][72]
  u16* Fw = lds + wave * 4352;  // pro/epilogue fixup [32][136] (overlays Ks/Vs)

  const float qscale = 0.125f * 1.4426950408889634f;  // dh^-0.5 * log2(e)

  // ---- issue chunk-0 K/V loads first; in flight during whole Q-proj ----
  const int kkey = tid >> 2, kseg = tid & 3;  // K: 64 rows x 4 segs of 32 u16
  const int vc = tid >> 1, vseg = tid & 1;    // V: 128 rows x 2 segs of 32 u16
  const u16* ksrc = Kb + (b * 1024 + kkey) * 128 + kseg * 32;
  const u16* vsrc = Vt + (b * 128 + vc) * 1024 + vseg * 32;
  uint4 kr0 = ((const uint4*)ksrc)[0], kr1 = ((const uint4*)ksrc)[1],
        kr2 = ((const uint4*)ksrc)[2], kr3 = ((const uint4*)ksrc)[3];
  uint4 vr0 = ((const uint4*)vsrc)[0], vr1 = ((const uint4*)vsrc)[1],
        vr2 = ((const uint4*)vsrc)[2], vr3 = ((const uint4*)vsrc)[3];

  // ---- Q-proj (16x16, 2 mt sub-blocks): D = Q^T[c][q] -> Fw[q][c] ----
#pragma unroll
  for (int mt = 0; mt < 2; ++mt) {
    short8 xb[4];
#pragma unroll
    for (int kc = 0; kc < 4; ++kc)
      xb[kc] = ld8(x, (b * 16384 + row0 + wrow + mt * 16 + l16) * 128 + kc * 32 + quad * 8,
                   isf32);
#pragma unroll
    for (int nt = 0; nt < 8; ++nt) {
      f32x4 qa = (f32x4){0.f, 0.f, 0.f, 0.f};
#pragma unroll
      for (int kc = 0; kc < 4; ++kc) {
        short8 w = *(const short8*)(WqT + (nt * 16 + l16) * 128 + kc * 32 + quad * 8);
        qa = MFMA16(w, xb[kc], qa);  // A=W^T[c][k], B=x[q][k] -> D=Q^T[c][q]
      }
      uint2 pk = {pk2(qa[0] * qscale, qa[1] * qscale), pk2(qa[2] * qscale, qa[3] * qscale)};
      *(uint2*)&Fw[(mt * 16 + l16) * 136 + nt * 16 + quad * 4] = pk;  // Qst[q][c]
    }
  }
  // Q B-frags for 32x32: lane(q32,hi) holds Q[q32][h*64+s*16+hi*8 ..+7]
  short8 qf[2][4];
#pragma unroll
  for (int h = 0; h < 2; ++h)
#pragma unroll
    for (int s = 0; s < 4; ++s)
      qf[h][s] = *(const short8*)&Fw[q32 * 136 + h * 64 + s * 16 + hi * 8];
  __syncthreads();  // all Fw reads done before first Ks/Vs commit

  f32x16 o[2][2];
#pragma unroll
  for (int h = 0; h < 2; ++h)
#pragma unroll
    for (int dt = 0; dt < 2; ++dt)
#pragma unroll
      for (int r = 0; r < 16; ++r) o[h][dt][r] = 0.f;
  float l[2] = {0.f, 0.f};

  for (int ch = 0; ch < 16; ++ch) {
    {  // commit staged regs -> LDS
      uint4* kd = (uint4*)&Ks[kkey * 136 + kseg * 32];
      kd[0] = kr0; kd[1] = kr1; kd[2] = kr2; kd[3] = kr3;
      uint4* vd = (uint4*)&Vs[vc * 72 + vseg * 32];
      vd[0] = vr0; vd[1] = vr1; vd[2] = vr2; vd[3] = vr3;
    }
    __syncthreads();
    if (ch < 15) {  // T14: prefetch next chunk under this chunk's compute
      const u16* kn = ksrc + (ch + 1) * 8192;
      kr0 = ((const uint4*)kn)[0]; kr1 = ((const uint4*)kn)[1];
      kr2 = ((const uint4*)kn)[2]; kr3 = ((const uint4*)kn)[3];
      const u16* vn = vsrc + (ch + 1) * 64;
      vr0 = ((const uint4*)vn)[0]; vr1 = ((const uint4*)vn)[1];
      vr2 = ((const uint4*)vn)[2]; vr3 = ((const uint4*)vn)[3];
    }
#pragma unroll
    for (int h = 0; h < 2; ++h) {
      // ---- S^T per key-tile kt (rows=key, cols=q); exp2; pack P[q][key] ----
#pragma unroll
      for (int kt = 0; kt < 2; ++kt) {
        f32x16 S;
#pragma unroll
        for (int r = 0; r < 16; ++r) S[r] = 0.f;
#pragma unroll
        for (int s = 0; s < 4; ++s) {
          short8 kf = *(const short8*)&Ks[(kt * 32 + q32) * 136 + h * 64 + s * 16 + hi * 8];
          S = MFMA32(kf, qf[h][s], S);  // A=K[key][d], B=Q[q][d] -> D=S^T[key][q]
        }
        float lh = 0.f;
#pragma unroll
        for (int rp = 0; rp < 8; ++rp) {
          float p0 = exp2f(S[2 * rp]), p1 = exp2f(S[2 * rp + 1]);
          lh += p0 + p1;
          // D rows r=2rp,2rp+1: key = 2*(rp&1) + 8*(rp>>1) + 4*hi (+1)
          *(unsigned*)&Pw[q32 * 72 + kt * 32 + (rp >> 1) * 8 + hi * 4 + (rp & 1) * 2] =
              pk2(p0, p1);
        }
        l[h] += lh;
      }
      // ---- O^T += V^T x P ----
      short8 pf[4];
#pragma unroll
      for (int s = 0; s < 4; ++s)
        pf[s] = *(const short8*)&Pw[q32 * 72 + s * 16 + hi * 8];
      __builtin_amdgcn_s_setprio(1);
#pragma unroll
      for (int dt = 0; dt < 2; ++dt)
#pragma unroll
        for (int s = 0; s < 4; ++s) {
          short8 vf = *(const short8*)&Vs[(h * 64 + dt * 32 + q32) * 72 + s * 16 + hi * 8];
          o[h][dt] = MFMA32(vf, pf[s], o[h][dt]);  // A=V^T[d][key], B=P[q][key]
        }
      __builtin_amdgcn_s_setprio(0);
    }
    __syncthreads();  // readers done before next commit (also fences epilogue)
  }

  // ---- softmax denom (half-wave partner holds the other 16 key-rows) ----
#pragma unroll
  for (int h = 0; h < 2; ++h) {
    float t = l[h];
    t += __shfl_xor(t, 32, 64);
    const float inv = 1.0f / t;
#pragma unroll
    for (int dt = 0; dt < 2; ++dt)
#pragma unroll
      for (int r = 0; r < 16; ++r) o[h][dt][r] *= inv;
  }

  // ---- epilogue: packed O^T -> Fw[q][d] -> 16x16 A-frags -> @Wproj ----
  // (loop's final barrier fences Ks/Vs readers before the Fw overlay writes)
#pragma unroll
  for (int h = 0; h < 2; ++h)
#pragma unroll
    for (int dt = 0; dt < 2; ++dt)
#pragma unroll
      for (int rp = 0; rp < 8; ++rp) {
        // D rows r=2rp,2rp+1 -> d = h*64 + dt*32 + 2*(rp&1) + 8*(rp>>1) + 4*hi
        *(unsigned*)&Fw[q32 * 136 + h * 64 + dt * 32 + (rp >> 1) * 8 + hi * 4 +
                        (rp & 1) * 2] = pk2(o[h][dt][2 * rp], o[h][dt][2 * rp + 1]);
      }
#pragma unroll
  for (int mt = 0; mt < 2; ++mt) {
    short8 of[4];
#pragma unroll
    for (int kc = 0; kc < 4; ++kc)
      of[kc] = *(const short8*)&Fw[(mt * 16 + l16) * 136 + kc * 32 + quad * 8];
#pragma unroll
    for (int nt = 0; nt < 8; ++nt) {
      f32x4 pa = (f32x4){0.f, 0.f, 0.f, 0.f};
#pragma unroll
      for (int kc = 0; kc < 4; ++kc) {
        short8 w = *(const short8*)(WpT + (nt * 16 + l16) * 128 + kc * 32 + quad * 8);
        pa = MFMA16(of[kc], w, pa);  // A=O[q][d], B=Wp^T[c][d] -> D=[q][c]
      }
#pragma unroll
      for (int rr = 0; rr < 4; ++rr)
        out[(b * 16384 + row0 + wrow + mt * 16 + quad * 4 + rr) * 128 + nt * 16 + l16] =
            pa[rr];
    }
  }
}

// ---------------------------------------------------------------------------
extern "C" void kernel_launch(void* const* d_in, const int* in_sizes, int n_in,
                              void* d_out, int out_size, void* d_ws, size_t ws_size,
                              hipStream_t stream) {
  (void)in_sizes; (void)n_in; (void)out_size; (void)ws_size;
  const void* x = d_in[0];
  const void* Wq = d_in[1];
  const void* Wk = d_in[2];
  const void* Wv = d_in[3];
  const void* Wp = d_in[4];
  const void* srk = d_in[5];
  const void* sbias = d_in[6];
  const void* gamma = d_in[7];
  const void* beta = d_in[8];
  float* out = (float*)d_out;
  u16* ws = (u16*)d_ws;

  u16* WcT = ws;
  u16* WqT = ws + 262144;
  u16* WkT = ws + 278528;
  u16* WvT = ws + 294912;
  u16* WpT = ws + 311296;
  u16* Kb = ws + 327680;
  u16* Vt = ws + 851968;

  prep_kernel<<<dim3(1280), dim3(256), 0, stream>>>(srk, Wq, Wk, Wv, Wp, x, WcT);
  conv_ln_kv_kernel<<<dim3(256), dim3(1024), 16 * 16 * 128 * 4 + 16 * 136 * 2, stream>>>(
      x, WcT, sbias, gamma, beta, WkT, WvT, Kb, Vt);
  attn_kernel<<<dim3(512), dim3(256), (64 * 136 + 128 * 72 + 4 * 2304) * 2, stream>>>(
      x, WqT, WpT, Kb, Vt, out);
}

// Round 11
// 209.610 us; speedup vs baseline: 1.5783x; 1.5783x over previous
//
#include <hip/hip_runtime.h>
#include <hip/hip_bf16.h>

typedef unsigned short u16;
typedef __attribute__((ext_vector_type(8))) short short8;
typedef __attribute__((ext_vector_type(4))) float f32x4;
typedef __attribute__((ext_vector_type(2))) float f32x2;
typedef __attribute__((ext_vector_type(16))) float f32x16;

#define MFMA16(a, b, c) __builtin_amdgcn_mfma_f32_16x16x32_bf16((a), (b), (c), 0, 0, 0)
#define MFMA32(a, b, c) __builtin_amdgcn_mfma_f32_32x32x16_bf16((a), (b), (c), 0, 0, 0)

__device__ __forceinline__ u16 f2bf(float f) {
  __hip_bfloat16 h = __float2bfloat16(f);
  u16 r;
  __builtin_memcpy(&r, &h, 2);
  return r;
}
__device__ __forceinline__ float bf2f(u16 h) {
  unsigned u = ((unsigned)h) << 16;
  float f;
  __builtin_memcpy(&f, &u, 4);
  return f;
}
// Single-instruction packed f32x2 -> bf16x2 (gfx950 v_cvt_pk_bf16_f32, RNE).
__device__ __forceinline__ unsigned pk2(float a, float b) {
  unsigned r;
  asm("v_cvt_pk_bf16_f32 %0, %1, %2" : "=v"(r) : "v"(a), "v"(b));
  return r;
}
// Load 8 consecutive source elements as bf16 short8 from f32 or bf16 storage.
__device__ __forceinline__ short8 ld8(const void* src, int idx, int isf32) {
  short8 v;
  if (isf32) {
    const float4* s = (const float4*)((const float*)src + idx);
    float4 p0 = s[0], p1 = s[1];
    unsigned d0 = pk2(p0.x, p0.y), d1 = pk2(p0.z, p0.w);
    unsigned d2 = pk2(p1.x, p1.y), d3 = pk2(p1.z, p1.w);
    uint4 dd = {d0, d1, d2, d3};
    __builtin_memcpy(&v, &dd, 16);
  } else {
    v = *(const short8*)((const u16*)src + idx);
  }
  return v;
}
__device__ __forceinline__ float ld1(const void* src, int idx, int isf32) {
  return isf32 ? ((const float*)src)[idx] : bf2f(((const u16*)src)[idx]);
}
// Per-block input-dtype detect (wave-uniform; f32 halves have hot exponents).
__device__ __forceinline__ int detect_isf32(const u16* xw) {
  int lane = threadIdx.x & 63;
  int cnt = 0;
#pragma unroll
  for (int i = 0; i < 16; ++i) {
    u16 w = xw[lane * 16 + i];
    cnt += (((w >> 7) & 0xFF) >= 0xC0) ? 1 : 0;
  }
#pragma unroll
  for (int off = 1; off < 64; off <<= 1) cnt += __shfl_xor(cnt, off, 64);
  return cnt >= 32;
}

// ---------------------------------------------------------------------------
// ws layout (u16 elements):
//   WcT [16][128cout][128cin]  @ 0
//   WqT/WkT/WvT/WpT [128][128] @ 262144/278528/294912/311296
//   Kb  [4][1024][128]         @ 327680
//   Vt  [4][128][1024]         @ 851968
// ---------------------------------------------------------------------------
// Re-enumerated so the f32 READ side is coalesced (gid == src index, 4-B
// stride); the cheap 2-B writes take the scatter instead (stores don't stall).
__global__ void prep_kernel(const void* __restrict__ srk, const void* __restrict__ Wq,
                            const void* __restrict__ Wk, const void* __restrict__ Wv,
                            const void* __restrict__ Wp, const void* __restrict__ x,
                            u16* __restrict__ WcT) {
  const int isf32 = detect_isf32((const u16*)x);
  int gid = blockIdx.x * 256 + threadIdx.x;
  if (gid >= 327680) return;
  float v;
  int dst;
  if (gid < 262144) {
    int mat = gid >> 14, cin = (gid >> 7) & 127, cout = gid & 127;
    v = ld1(srk, gid, isf32);  // mat*16384 + cin*128 + cout == gid (coalesced)
    dst = mat * 16384 + cout * 128 + cin;
  } else {
    int g2 = gid - 262144;
    int mat = g2 >> 14, cin = (g2 >> 7) & 127, cout = g2 & 127;
    const void* src = (mat == 0) ? Wq : (mat == 1) ? Wk : (mat == 2) ? Wv : Wp;
    v = ld1(src, cin * 128 + cout, isf32);  // == g2 & 16383 (coalesced)
    dst = 262144 + mat * 16384 + cout * 128 + cin;
  }
  WcT[dst] = f2bf(v);
}

// ---------------------------------------------------------------------------
// Conv (stride-4 4x4 'SAME' == patch GEMM) + bias + LayerNorm + fused K/V.
// Grid 256 WGs x 1024 thr (16 waves). Wave w owns conv tap rs=w (K-split 16).
// Vt store packed (one 8-B uint2 per lane). Unchanged from round 9.
// ---------------------------------------------------------------------------
__launch_bounds__(1024, 4)
__global__ void conv_ln_kv_kernel(const void* __restrict__ x, const u16* __restrict__ wcT,
                                  const void* __restrict__ sr_bias,
                                  const void* __restrict__ gamma,
                                  const void* __restrict__ beta,
                                  const u16* __restrict__ WkT, const u16* __restrict__ WvT,
                                  u16* __restrict__ Kb, u16* __restrict__ Vt) {
  extern __shared__ char cws[];
  float* Racc = (float*)cws;                    // [16][16][128] f32 = 128 KB
  u16* Xs = (u16*)(cws + 16 * 16 * 128 * 4);    // [16][136] bf16
  const int isf32 = detect_isf32((const u16*)x);
  const int tid = threadIdx.x;
  const int wave = tid >> 6, lane = tid & 63;
  const int quad = lane >> 4, l16 = lane & 15;
  const int g = blockIdx.x;  // rows g*16 .. g*16+15

  const int row = g * 16 + l16;
  const int pb = row >> 10, rem = row & 1023, oh = rem >> 5, ow = rem & 31;
  const int xbase = ((pb * 128 + oh * 4) * 128 + ow * 4) * 128;

  f32x4 acc[8];
#pragma unroll
  for (int i = 0; i < 8; ++i) acc[i] = (f32x4){0.f, 0.f, 0.f, 0.f};

  {  // tap rs = wave (r = wave>>2, s = wave&3)
    const int r = wave >> 2, sc = wave & 3;
    short8 a[4];
#pragma unroll
    for (int kc = 0; kc < 4; ++kc)
      a[kc] = ld8(x, xbase + r * 16384 + sc * 128 + kc * 32 + quad * 8, isf32);
#pragma unroll
    for (int nt = 0; nt < 8; ++nt)
#pragma unroll
      for (int kc = 0; kc < 4; ++kc) {
        short8 bw = *(const short8*)(wcT + wave * 16384 + (nt * 16 + l16) * 128 +
                                     kc * 32 + quad * 8);
        acc[nt] = MFMA16(a[kc], bw, acc[nt]);
      }
  }
  // partials -> LDS
#pragma unroll
  for (int nt = 0; nt < 8; ++nt)
#pragma unroll
    for (int rr = 0; rr < 4; ++rr)
      Racc[(wave * 16 + quad * 4 + rr) * 128 + nt * 16 + l16] = acc[nt][rr];
  __syncthreads();

  // reduce 16 wave-slices; wave owns row `wave`, lane owns 2 cols at lane*2
  {
    const int lrow = wave, c0 = lane * 2;
    f32x2 rsum = (f32x2){0.f, 0.f};
#pragma unroll
    for (int w = 0; w < 16; ++w) {
      f32x2 t = *(const f32x2*)&Racc[(w * 16 + lrow) * 128 + c0];
      rsum[0] += t[0];
      rsum[1] += t[1];
    }
    float v0 = rsum[0] + ld1(sr_bias, c0, isf32);
    float v1 = rsum[1] + ld1(sr_bias, c0 + 1, isf32);
    float sum = v0 + v1, sum2 = v0 * v0 + v1 * v1;
#pragma unroll
    for (int off = 1; off < 64; off <<= 1) {
      sum += __shfl_xor(sum, off, 64);
      sum2 += __shfl_xor(sum2, off, 64);
    }
    const float mu = sum * (1.f / 128.f);
    const float var = sum2 * (1.f / 128.f) - mu * mu;
    const float rinv = rsqrtf(fmaxf(var, 0.f) + 1e-6f);
    float y0 = (v0 - mu) * rinv * ld1(gamma, c0, isf32) + ld1(beta, c0, isf32);
    float y1 = (v1 - mu) * rinv * ld1(gamma, c0 + 1, isf32) + ld1(beta, c0 + 1, isf32);
    *(unsigned*)&Xs[lrow * 136 + c0] = pk2(y0, y1);
  }
  __syncthreads();

  // fused K/V projection: wave w -> nt = w>>1; even waves K, odd waves V
  short8 a2[4];
#pragma unroll
  for (int kc = 0; kc < 4; ++kc)
    a2[kc] = *(const short8*)&Xs[l16 * 136 + kc * 32 + quad * 8];
  const u16* Wm = (wave & 1) ? WvT : WkT;
  const int nt = wave >> 1;
  f32x4 a3 = (f32x4){0.f, 0.f, 0.f, 0.f};
#pragma unroll
  for (int kc = 0; kc < 4; ++kc) {
    short8 bm = *(const short8*)(Wm + (nt * 16 + l16) * 128 + kc * 32 + quad * 8);
    a3 = MFMA16(a2[kc], bm, a3);
  }
  const int rowg0 = g * 16 + quad * 4;            // 4-aligned; never crosses 1024
  const int b0 = rowg0 >> 10, key0 = rowg0 & 1023;
  const int c = nt * 16 + l16;
  if (wave & 1) {
    uint2 pv = {pk2(a3[0], a3[1]), pk2(a3[2], a3[3])};
    *(uint2*)&Vt[(b0 * 128 + c) * 1024 + key0] = pv;  // 8-B aligned packed store
  } else {
#pragma unroll
    for (int rr = 0; rr < 4; ++rr) Kb[(rowg0 + rr) * 128 + c] = f2bf(a3[rr]);
  }
}

// ---------------------------------------------------------------------------
// Fused attention, 32x32x16 MFMA core. Grid 512 x 256 thr (4 waves x 32 q).
// Base = round-9 (102.5 us, VGPR 120, launch_bounds(256,2) — REVERTED from
// round-10's (256,3) which spilled: unified VGPR+AGPR ~184 > 170 cap).
// NEW: T2 XOR-swizzle on all in-loop LDS accesses. Ks stride 136 u16 = 68 dw
// == 4 (mod 32) and Vs/Pw stride 72 u16 = 36 dw == 4 (mod 32) -> rows r,r+8,
// r+16,r+24 at the same col hit the same bank: 4-way conflict on every
// kf/vf/pf read and staging/P write (SQ_LDS_BANK_CONFLICT 7.9e6 ~= 13 us).
// Fix: phys_idx = logical_idx ^ (((row>>3)&3)<<3)  [u16 units; flips byte
// bits 4-5] applied identically on writer and reader (reg-staged writes make
// both-sides swizzle legal). Regions are 32-u16 multiples so XOR never
// crosses; accesses stay 16-B/4-B aligned. For readers, (row>>3)&3 reduces
// to (q32>>3)&3 for every row family used (kt*32+q32, h*64+dt*32+q32, q32).
// ---------------------------------------------------------------------------
__launch_bounds__(256, 2)
__global__ void attn_kernel(const void* __restrict__ x, const u16* __restrict__ WqT,
                            const u16* __restrict__ WpT, const u16* __restrict__ Kb,
                            const u16* __restrict__ Vt, float* __restrict__ out) {
  extern __shared__ u16 lds[];
  u16* Ks = lds;             // [64][136]  8704 el (region mult of 32)
  u16* Vs = Ks + 64 * 136;   // [128][72]  9216 el (base 8704 = 272*32)
  u16* Pp = Vs + 128 * 72;   // [4][2304]  per-wave P scratch [32][72]
  const int isf32 = detect_isf32((const u16*)x);
  const int tid = threadIdx.x;
  const int wave = tid >> 6, lane = tid & 63;
  const int quad = lane >> 4, l16 = lane & 15;   // 16x16 frag indexing
  const int q32 = lane & 31, hi = lane >> 5;     // 32x32 frag indexing
  const int swz = (blockIdx.x & 7) * 64 + (blockIdx.x >> 3);  // XCD-contiguous
  const int b = swz >> 7;
  const int row0 = (swz & 127) * 128;
  const int wrow = wave * 32;
  u16* Pw = Pp + wave * 2304;   // in-loop P scratch [32][72]
  u16* Fw = lds + wave * 4352;  // pro/epilogue fixup [32][136] (overlays Ks/Vs)

  const float qscale = 0.125f * 1.4426950408889634f;  // dh^-0.5 * log2(e)
  const int q8 = ((q32 >> 3) & 3) << 3;  // read-side swizzle (row-derived)

  // ---- issue chunk-0 K/V loads first; in flight during whole Q-proj ----
  const int kkey = tid >> 2, kseg = tid & 3;  // K: 64 rows x 4 segs of 32 u16
  const int vc = tid >> 1, vseg = tid & 1;    // V: 128 rows x 2 segs of 32 u16
  const int kxor = ((kkey >> 3) & 3) << 3;    // write-side swizzle (K rows)
  const int vxor = ((vc >> 3) & 3) << 3;      // write-side swizzle (V rows)
  const u16* ksrc = Kb + (b * 1024 + kkey) * 128 + kseg * 32;
  const u16* vsrc = Vt + (b * 128 + vc) * 1024 + vseg * 32;
  uint4 kr0 = ((const uint4*)ksrc)[0], kr1 = ((const uint4*)ksrc)[1],
        kr2 = ((const uint4*)ksrc)[2], kr3 = ((const uint4*)ksrc)[3];
  uint4 vr0 = ((const uint4*)vsrc)[0], vr1 = ((const uint4*)vsrc)[1],
        vr2 = ((const uint4*)vsrc)[2], vr3 = ((const uint4*)vsrc)[3];

  // ---- Q-proj (16x16, 2 mt sub-blocks): D = Q^T[c][q] -> Fw[q][c] ----
#pragma unroll
  for (int mt = 0; mt < 2; ++mt) {
    short8 xb[4];
#pragma unroll
    for (int kc = 0; kc < 4; ++kc)
      xb[kc] = ld8(x, (b * 16384 + row0 + wrow + mt * 16 + l16) * 128 + kc * 32 + quad * 8,
                   isf32);
#pragma unroll
    for (int nt = 0; nt < 8; ++nt) {
      f32x4 qa = (f32x4){0.f, 0.f, 0.f, 0.f};
#pragma unroll
      for (int kc = 0; kc < 4; ++kc) {
        short8 w = *(const short8*)(WqT + (nt * 16 + l16) * 128 + kc * 32 + quad * 8);
        qa = MFMA16(w, xb[kc], qa);  // A=W^T[c][k], B=x[q][k] -> D=Q^T[c][q]
      }
      uint2 pk = {pk2(qa[0] * qscale, qa[1] * qscale), pk2(qa[2] * qscale, qa[3] * qscale)};
      *(uint2*)&Fw[(mt * 16 + l16) * 136 + nt * 16 + quad * 4] = pk;  // Qst[q][c]
    }
  }
  // Q B-frags for 32x32: lane(q32,hi) holds Q[q32][h*64+s*16+hi*8 ..+7]
  short8 qf[2][4];
#pragma unroll
  for (int h = 0; h < 2; ++h)
#pragma unroll
    for (int s = 0; s < 4; ++s)
      qf[h][s] = *(const short8*)&Fw[q32 * 136 + h * 64 + s * 16 + hi * 8];
  __syncthreads();  // all Fw reads done before first Ks/Vs commit

  f32x16 o[2][2];
#pragma unroll
  for (int h = 0; h < 2; ++h)
#pragma unroll
    for (int dt = 0; dt < 2; ++dt)
#pragma unroll
      for (int r = 0; r < 16; ++r) o[h][dt][r] = 0.f;
  float l[2] = {0.f, 0.f};

  for (int ch = 0; ch < 16; ++ch) {
    {  // commit staged regs -> LDS (swizzled destinations)
      const int kb0 = kkey * 136 + kseg * 32;
      *(uint4*)&Ks[(kb0 + 0) ^ kxor] = kr0;
      *(uint4*)&Ks[(kb0 + 8) ^ kxor] = kr1;
      *(uint4*)&Ks[(kb0 + 16) ^ kxor] = kr2;
      *(uint4*)&Ks[(kb0 + 24) ^ kxor] = kr3;
      const int vb0 = vc * 72 + vseg * 32;
      *(uint4*)&Vs[(vb0 + 0) ^ vxor] = vr0;
      *(uint4*)&Vs[(vb0 + 8) ^ vxor] = vr1;
      *(uint4*)&Vs[(vb0 + 16) ^ vxor] = vr2;
      *(uint4*)&Vs[(vb0 + 24) ^ vxor] = vr3;
    }
    __syncthreads();
    if (ch < 15) {  // T14: prefetch next chunk under this chunk's compute
      const u16* kn = ksrc + (ch + 1) * 8192;
      kr0 = ((const uint4*)kn)[0]; kr1 = ((const uint4*)kn)[1];
      kr2 = ((const uint4*)kn)[2]; kr3 = ((const uint4*)kn)[3];
      const u16* vn = vsrc + (ch + 1) * 64;
      vr0 = ((const uint4*)vn)[0]; vr1 = ((const uint4*)vn)[1];
      vr2 = ((const uint4*)vn)[2]; vr3 = ((const uint4*)vn)[3];
    }
#pragma unroll
    for (int h = 0; h < 2; ++h) {
      // ---- S^T per key-tile kt (rows=key, cols=q); exp2; pack P[q][key] ----
#pragma unroll
      for (int kt = 0; kt < 2; ++kt) {
        f32x16 S;
#pragma unroll
        for (int r = 0; r < 16; ++r) S[r] = 0.f;
#pragma unroll
        for (int s = 0; s < 4; ++s) {
          short8 kf = *(const short8*)&Ks[((kt * 32 + q32) * 136 + h * 64 + s * 16 +
                                           hi * 8) ^ q8];
          S = MFMA32(kf, qf[h][s], S);  // A=K[key][d], B=Q[q][d] -> D=S^T[key][q]
        }
        float lh = 0.f;
#pragma unroll
        for (int rp = 0; rp < 8; ++rp) {
          float p0 = exp2f(S[2 * rp]), p1 = exp2f(S[2 * rp + 1]);
          lh += p0 + p1;
          // D rows r=2rp,2rp+1: key = 2*(rp&1) + 8*(rp>>1) + 4*hi (+1)
          *(unsigned*)&Pw[(q32 * 72 + kt * 32 + (rp >> 1) * 8 + hi * 4 + (rp & 1) * 2) ^
                          q8] = pk2(p0, p1);
        }
        l[h] += lh;
      }
      // ---- O^T += V^T x P ----
      short8 pf[4];
#pragma unroll
      for (int s = 0; s < 4; ++s)
        pf[s] = *(const short8*)&Pw[(q32 * 72 + s * 16 + hi * 8) ^ q8];
      __builtin_amdgcn_s_setprio(1);
#pragma unroll
      for (int dt = 0; dt < 2; ++dt)
#pragma unroll
        for (int s = 0; s < 4; ++s) {
          short8 vf = *(const short8*)&Vs[((h * 64 + dt * 32 + q32) * 72 + s * 16 +
                                           hi * 8) ^ q8];
          o[h][dt] = MFMA32(vf, pf[s], o[h][dt]);  // A=V^T[d][key], B=P[q][key]
        }
      __builtin_amdgcn_s_setprio(0);
    }
    __syncthreads();  // readers done before next commit (also fences epilogue)
  }

  // ---- softmax denom (half-wave partner holds the other 16 key-rows) ----
#pragma unroll
  for (int h = 0; h < 2; ++h) {
    float t = l[h];
    t += __shfl_xor(t, 32, 64);
    const float inv = 1.0f / t;
#pragma unroll
    for (int dt = 0; dt < 2; ++dt)
#pragma unroll
      for (int r = 0; r < 16; ++r) o[h][dt][r] *= inv;
  }

  // ---- epilogue: packed O^T -> Fw[q][d] -> 16x16 A-frags -> @Wproj ----
  // (loop's final barrier fences Ks/Vs readers before the Fw overlay writes)
#pragma unroll
  for (int h = 0; h < 2; ++h)
#pragma unroll
    for (int dt = 0; dt < 2; ++dt)
#pragma unroll
      for (int rp = 0; rp < 8; ++rp) {
        // D rows r=2rp,2rp+1 -> d = h*64 + dt*32 + 2*(rp&1) + 8*(rp>>1) + 4*hi
        *(unsigned*)&Fw[q32 * 136 + h * 64 + dt * 32 + (rp >> 1) * 8 + hi * 4 +
                        (rp & 1) * 2] = pk2(o[h][dt][2 * rp], o[h][dt][2 * rp + 1]);
      }
#pragma unroll
  for (int mt = 0; mt < 2; ++mt) {
    short8 of[4];
#pragma unroll
    for (int kc = 0; kc < 4; ++kc)
      of[kc] = *(const short8*)&Fw[(mt * 16 + l16) * 136 + kc * 32 + quad * 8];
#pragma unroll
    for (int nt = 0; nt < 8; ++nt) {
      f32x4 pa = (f32x4){0.f, 0.f, 0.f, 0.f};
#pragma unroll
      for (int kc = 0; kc < 4; ++kc) {
        short8 w = *(const short8*)(WpT + (nt * 16 + l16) * 128 + kc * 32 + quad * 8);
        pa = MFMA16(of[kc], w, pa);  // A=O[q][d], B=Wp^T[c][d] -> D=[q][c]
      }
#pragma unroll
      for (int rr = 0; rr < 4; ++rr)
        out[(b * 16384 + row0 + wrow + mt * 16 + quad * 4 + rr) * 128 + nt * 16 + l16] =
            pa[rr];
    }
  }
}

// ---------------------------------------------------------------------------
extern "C" void kernel_launch(void* const* d_in, const int* in_sizes, int n_in,
                              void* d_out, int out_size, void* d_ws, size_t ws_size,
                              hipStream_t stream) {
  (void)in_sizes; (void)n_in; (void)out_size; (void)ws_size;
  const void* x = d_in[0];
  const void* Wq = d_in[1];
  const void* Wk = d_in[2];
  const void* Wv = d_in[3];
  const void* Wp = d_in[4];
  const void* srk = d_in[5];
  const void* sbias = d_in[6];
  const void* gamma = d_in[7];
  const void* beta = d_in[8];
  float* out = (float*)d_out;
  u16* ws = (u16*)d_ws;

  u16* WcT = ws;
  u16* WqT = ws + 262144;
  u16* WkT = ws + 278528;
  u16* WvT = ws + 294912;
  u16* WpT = ws + 311296;
  u16* Kb = ws + 327680;
  u16* Vt = ws + 851968;

  prep_kernel<<<dim3(1280), dim3(256), 0, stream>>>(srk, Wq, Wk, Wv, Wp, x, WcT);
  conv_ln_kv_kernel<<<dim3(256), dim3(1024), 16 * 16 * 128 * 4 + 16 * 136 * 2, stream>>>(
      x, WcT, sbias, gamma, beta, WkT, WvT, Kb, Vt);
  attn_kernel<<<dim3(512), dim3(256), (64 * 136 + 128 * 72 + 4 * 2304) * 2, stream>>>(
      x, WqT, WpT, Kb, Vt, out);
}

// Round 13
// 199.631 us; speedup vs baseline: 1.6572x; 1.0500x over previous
//
#include <hip/hip_runtime.h>
#include <hip/hip_bf16.h>

typedef unsigned short u16;
typedef __attribute__((ext_vector_type(8))) short short8;
typedef __attribute__((ext_vector_type(4))) float f32x4;
typedef __attribute__((ext_vector_type(2))) float f32x2;
typedef __attribute__((ext_vector_type(16))) float f32x16;

#define MFMA16(a, b, c) __builtin_amdgcn_mfma_f32_16x16x32_bf16((a), (b), (c), 0, 0, 0)
#define MFMA32(a, b, c) __builtin_amdgcn_mfma_f32_32x32x16_bf16((a), (b), (c), 0, 0, 0)

__device__ __forceinline__ u16 f2bf(float f) {
  __hip_bfloat16 h = __float2bfloat16(f);
  u16 r;
  __builtin_memcpy(&r, &h, 2);
  return r;
}
__device__ __forceinline__ float bf2f(u16 h) {
  unsigned u = ((unsigned)h) << 16;
  float f;
  __builtin_memcpy(&f, &u, 4);
  return f;
}
// Single-instruction packed f32x2 -> bf16x2 (gfx950 v_cvt_pk_bf16_f32, RNE).
__device__ __forceinline__ unsigned pk2(float a, float b) {
  unsigned r;
  asm("v_cvt_pk_bf16_f32 %0, %1, %2" : "=v"(r) : "v"(a), "v"(b));
  return r;
}
// Load 8 consecutive source elements as bf16 short8 from f32 or bf16 storage.
__device__ __forceinline__ short8 ld8(const void* src, int idx, int isf32) {
  short8 v;
  if (isf32) {
    const float4* s = (const float4*)((const float*)src + idx);
    float4 p0 = s[0], p1 = s[1];
    unsigned d0 = pk2(p0.x, p0.y), d1 = pk2(p0.z, p0.w);
    unsigned d2 = pk2(p1.x, p1.y), d3 = pk2(p1.z, p1.w);
    uint4 dd = {d0, d1, d2, d3};
    __builtin_memcpy(&v, &dd, 16);
  } else {
    v = *(const short8*)((const u16*)src + idx);
  }
  return v;
}
__device__ __forceinline__ float ld1(const void* src, int idx, int isf32) {
  return isf32 ? ((const float*)src)[idx] : bf2f(((const u16*)src)[idx]);
}
// Per-block input-dtype detect (wave-uniform; f32 halves have hot exponents).
__device__ __forceinline__ int detect_isf32(const u16* xw) {
  int lane = threadIdx.x & 63;
  int cnt = 0;
#pragma unroll
  for (int i = 0; i < 16; ++i) {
    u16 w = xw[lane * 16 + i];
    cnt += (((w >> 7) & 0xFF) >= 0xC0) ? 1 : 0;
  }
#pragma unroll
  for (int off = 1; off < 64; off <<= 1) cnt += __shfl_xor(cnt, off, 64);
  return cnt >= 32;
}

// ---------------------------------------------------------------------------
// ws layout (u16 elements):
//   WcT [16][128cout][128cin]  @ 0
//   WqT/WkT/WvT/WpT [128][128] @ 262144/278528/294912/311296
//   Kb  [4][1024][128]         @ 327680
//   Vt  [4][128][1024]         @ 851968
// ---------------------------------------------------------------------------
// Coalesced f32 reads (gid == src index); 2-B writes take the scatter.
__global__ void prep_kernel(const void* __restrict__ srk, const void* __restrict__ Wq,
                            const void* __restrict__ Wk, const void* __restrict__ Wv,
                            const void* __restrict__ Wp, const void* __restrict__ x,
                            u16* __restrict__ WcT) {
  const int isf32 = detect_isf32((const u16*)x);
  int gid = blockIdx.x * 256 + threadIdx.x;
  if (gid >= 327680) return;
  float v;
  int dst;
  if (gid < 262144) {
    int mat = gid >> 14, cin = (gid >> 7) & 127, cout = gid & 127;
    v = ld1(srk, gid, isf32);  // mat*16384 + cin*128 + cout == gid (coalesced)
    dst = mat * 16384 + cout * 128 + cin;
  } else {
    int g2 = gid - 262144;
    int mat = g2 >> 14, cin = (g2 >> 7) & 127, cout = g2 & 127;
    const void* src = (mat == 0) ? Wq : (mat == 1) ? Wk : (mat == 2) ? Wv : Wp;
    v = ld1(src, cin * 128 + cout, isf32);  // == g2 & 16383 (coalesced)
    dst = 262144 + mat * 16384 + cout * 128 + cin;
  }
  WcT[dst] = f2bf(v);
}

// ---------------------------------------------------------------------------
// Conv (stride-4 4x4 'SAME' == patch GEMM) + bias + LayerNorm + fused K/V.
// Grid 256 WGs x 1024 thr (16 waves). Wave w owns conv tap rs=w (K-split 16).
// Vt store packed (one 8-B uint2 per lane). Unchanged from round 9.
// ---------------------------------------------------------------------------
__launch_bounds__(1024, 4)
__global__ void conv_ln_kv_kernel(const void* __restrict__ x, const u16* __restrict__ wcT,
                                  const void* __restrict__ sr_bias,
                                  const void* __restrict__ gamma,
                                  const void* __restrict__ beta,
                                  const u16* __restrict__ WkT, const u16* __restrict__ WvT,
                                  u16* __restrict__ Kb, u16* __restrict__ Vt) {
  extern __shared__ char cws[];
  float* Racc = (float*)cws;                    // [16][16][128] f32 = 128 KB
  u16* Xs = (u16*)(cws + 16 * 16 * 128 * 4);    // [16][136] bf16
  const int isf32 = detect_isf32((const u16*)x);
  const int tid = threadIdx.x;
  const int wave = tid >> 6, lane = tid & 63;
  const int quad = lane >> 4, l16 = lane & 15;
  const int g = blockIdx.x;  // rows g*16 .. g*16+15

  const int row = g * 16 + l16;
  const int pb = row >> 10, rem = row & 1023, oh = rem >> 5, ow = rem & 31;
  const int xbase = ((pb * 128 + oh * 4) * 128 + ow * 4) * 128;

  f32x4 acc[8];
#pragma unroll
  for (int i = 0; i < 8; ++i) acc[i] = (f32x4){0.f, 0.f, 0.f, 0.f};

  {  // tap rs = wave (r = wave>>2, s = wave&3)
    const int r = wave >> 2, sc = wave & 3;
    short8 a[4];
#pragma unroll
    for (int kc = 0; kc < 4; ++kc)
      a[kc] = ld8(x, xbase + r * 16384 + sc * 128 + kc * 32 + quad * 8, isf32);
#pragma unroll
    for (int nt = 0; nt < 8; ++nt)
#pragma unroll
      for (int kc = 0; kc < 4; ++kc) {
        short8 bw = *(const short8*)(wcT + wave * 16384 + (nt * 16 + l16) * 128 +
                                     kc * 32 + quad * 8);
        acc[nt] = MFMA16(a[kc], bw, acc[nt]);
      }
  }
  // partials -> LDS
#pragma unroll
  for (int nt = 0; nt < 8; ++nt)
#pragma unroll
    for (int rr = 0; rr < 4; ++rr)
      Racc[(wave * 16 + quad * 4 + rr) * 128 + nt * 16 + l16] = acc[nt][rr];
  __syncthreads();

  // reduce 16 wave-slices; wave owns row `wave`, lane owns 2 cols at lane*2
  {
    const int lrow = wave, c0 = lane * 2;
    f32x2 rsum = (f32x2){0.f, 0.f};
#pragma unroll
    for (int w = 0; w < 16; ++w) {
      f32x2 t = *(const f32x2*)&Racc[(w * 16 + lrow) * 128 + c0];
      rsum[0] += t[0];
      rsum[1] += t[1];
    }
    float v0 = rsum[0] + ld1(sr_bias, c0, isf32);
    float v1 = rsum[1] + ld1(sr_bias, c0 + 1, isf32);
    float sum = v0 + v1, sum2 = v0 * v0 + v1 * v1;
#pragma unroll
    for (int off = 1; off < 64; off <<= 1) {
      sum += __shfl_xor(sum, off, 64);
      sum2 += __shfl_xor(sum2, off, 64);
    }
    const float mu = sum * (1.f / 128.f);
    const float var = sum2 * (1.f / 128.f) - mu * mu;
    const float rinv = rsqrtf(fmaxf(var, 0.f) + 1e-6f);
    float y0 = (v0 - mu) * rinv * ld1(gamma, c0, isf32) + ld1(beta, c0, isf32);
    float y1 = (v1 - mu) * rinv * ld1(gamma, c0 + 1, isf32) + ld1(beta, c0 + 1, isf32);
    *(unsigned*)&Xs[lrow * 136 + c0] = pk2(y0, y1);
  }
  __syncthreads();

  // fused K/V projection: wave w -> nt = w>>1; even waves K, odd waves V
  short8 a2[4];
#pragma unroll
  for (int kc = 0; kc < 4; ++kc)
    a2[kc] = *(const short8*)&Xs[l16 * 136 + kc * 32 + quad * 8];
  const u16* Wm = (wave & 1) ? WvT : WkT;
  const int nt = wave >> 1;
  f32x4 a3 = (f32x4){0.f, 0.f, 0.f, 0.f};
#pragma unroll
  for (int kc = 0; kc < 4; ++kc) {
    short8 bm = *(const short8*)(Wm + (nt * 16 + l16) * 128 + kc * 32 + quad * 8);
    a3 = MFMA16(a2[kc], bm, a3);
  }
  const int rowg0 = g * 16 + quad * 4;            // 4-aligned; never crosses 1024
  const int b0 = rowg0 >> 10, key0 = rowg0 & 1023;
  const int c = nt * 16 + l16;
  if (wave & 1) {
    uint2 pv = {pk2(a3[0], a3[1]), pk2(a3[2], a3[3])};
    *(uint2*)&Vt[(b0 * 128 + c) * 1024 + key0] = pv;  // 8-B aligned packed store
  } else {
#pragma unroll
    for (int rr = 0; rr < 4; ++rr) Kb[(rowg0 + rr) * 128 + c] = f2bf(a3[rr]);
  }
}

// ---------------------------------------------------------------------------
// Fused attention, 32x32x16 core, HEAD-SPLIT waves. Grid 512 x 512 thr:
// 8 waves = 4 q-tiles x 2 heads; wave (qt,h) owns 32 q-rows x one head.
// r12 FIX: staging under-fill — with kseg/vseg segments of 16 u16, each
// thread must load TWO uint4 (16 u16), not one. r12 committed only half of
// Ks/Vs -> garbage -> NaN. This rev loads/commits kr0,kr1 / vr0,vr1
// (512 thr x 16 u16 = 8192 u16 = full 64x128 K tile and 128x64 V tile).
// Rationale (r11 diagnosis): latency-bound at 46% issue with 2 waves/SIMD.
// Head-split: (a) 4 waves/SIMD (16 waves/CU, LDS 72704 B = 2 WGs/CU),
// (b) per-wave chain halves, (c) accumulators halve -> persistent regs ~80,
// total ~110-120 under the (512,4) cap of 128 (r9 needed 120 with a 48-reg
// LARGER accumulator set). In-loop LDS index formulas byte-identical to the
// proven r8/r9 kernel. Epilogue: the two h-waves of a q-tile combine
// O-halves in shared Ew[32][136] (disjoint cols, one barrier), split Wproj.
// Keep: XCD swizzle, setprio, T14 prefetch.
// ---------------------------------------------------------------------------
__launch_bounds__(512, 4)
__global__ void attn_kernel(const void* __restrict__ x, const u16* __restrict__ WqT,
                            const u16* __restrict__ WpT, const u16* __restrict__ Kb,
                            const u16* __restrict__ Vt, float* __restrict__ out) {
  extern __shared__ u16 lds[];
  u16* Ks = lds;             // [64][136]   8704 el
  u16* Vs = Ks + 64 * 136;   // [128][72]   9216 el
  u16* Pp = Vs + 128 * 72;   // [8][2304]   per-wave P scratch [32][72]
  const int isf32 = detect_isf32((const u16*)x);
  const int tid = threadIdx.x;
  const int wave = tid >> 6, lane = tid & 63;
  const int quad = lane >> 4, l16 = lane & 15;   // 16x16 frag indexing
  const int q32 = lane & 31, hi = lane >> 5;     // 32x32 frag indexing
  const int qt = wave >> 1, h = wave & 1;        // q-tile, head
  const int swz = (blockIdx.x & 7) * 64 + (blockIdx.x >> 3);  // XCD-contiguous
  const int b = swz >> 7;
  const int row0 = (swz & 127) * 128;
  const int wrow = qt * 32;
  u16* Pw = Pp + wave * 2304;   // in-loop P scratch [32][72]
  u16* Fw = lds + wave * 2304;  // prologue Q-fixup [32][72] (overlays Ks/Vs/Pp)
  u16* Ew = lds + qt * 4352;    // epilogue O combine [32][136] per q-tile

  const float qscale = 0.125f * 1.4426950408889634f;  // dh^-0.5 * log2(e)

  // ---- issue chunk-0 K/V loads first; in flight during whole Q-proj ----
  const int kkey = tid >> 3, kseg = tid & 7;  // K: 64 rows x 8 segs of 16 u16
  const int vc = tid >> 2, vseg = tid & 3;    // V: 128 rows x 4 segs of 16 u16
  const u16* ksrc = Kb + (b * 1024 + kkey) * 128 + kseg * 16;
  const u16* vsrc = Vt + (b * 128 + vc) * 1024 + vseg * 16;
  uint4 kr0 = ((const uint4*)ksrc)[0], kr1 = ((const uint4*)ksrc)[1];
  uint4 vr0 = ((const uint4*)vsrc)[0], vr1 = ((const uint4*)vsrc)[1];

  // ---- Q-proj: wave (qt,h) computes its head's 64 Q-cols for 32 rows ----
#pragma unroll
  for (int mt = 0; mt < 2; ++mt) {
    short8 xb[4];
#pragma unroll
    for (int kc = 0; kc < 4; ++kc)
      xb[kc] = ld8(x, (b * 16384 + row0 + wrow + mt * 16 + l16) * 128 + kc * 32 + quad * 8,
                   isf32);
#pragma unroll
    for (int ntp = 0; ntp < 4; ++ntp) {
      f32x4 qa = (f32x4){0.f, 0.f, 0.f, 0.f};
#pragma unroll
      for (int kc = 0; kc < 4; ++kc) {
        short8 w = *(const short8*)(WqT + (h * 64 + ntp * 16 + l16) * 128 + kc * 32 +
                                    quad * 8);
        qa = MFMA16(w, xb[kc], qa);  // A=W^T[c][k], B=x[q][k] -> D=Q^T[c][q]
      }
      uint2 pk = {pk2(qa[0] * qscale, qa[1] * qscale), pk2(qa[2] * qscale, qa[3] * qscale)};
      *(uint2*)&Fw[(mt * 16 + l16) * 72 + ntp * 16 + quad * 4] = pk;  // Qst[q][c']
    }
  }
  // Q B-frags: lane(q32,hi) holds Q[q32][h*64 + s*16 + hi*8 ..+7]
  short8 qf[4];
#pragma unroll
  for (int s = 0; s < 4; ++s)
    qf[s] = *(const short8*)&Fw[q32 * 72 + s * 16 + hi * 8];
  __syncthreads();  // all Fw reads done before first Ks/Vs commit

  f32x16 o[2];
#pragma unroll
  for (int dt = 0; dt < 2; ++dt)
#pragma unroll
    for (int r = 0; r < 16; ++r) o[dt][r] = 0.f;
  float l = 0.f;

  for (int ch = 0; ch < 16; ++ch) {
    {  // commit staged regs -> LDS (two uint4 each = full 16-u16 segment)
      uint4* kd = (uint4*)&Ks[kkey * 136 + kseg * 16];
      kd[0] = kr0;
      kd[1] = kr1;
      uint4* vd = (uint4*)&Vs[vc * 72 + vseg * 16];
      vd[0] = vr0;
      vd[1] = vr1;
    }
    __syncthreads();
    if (ch < 15) {  // T14: prefetch next chunk under this chunk's compute
      const u16* kn = ksrc + (ch + 1) * 8192;
      kr0 = ((const uint4*)kn)[0];
      kr1 = ((const uint4*)kn)[1];
      const u16* vn = vsrc + (ch + 1) * 64;
      vr0 = ((const uint4*)vn)[0];
      vr1 = ((const uint4*)vn)[1];
    }
    // ---- S^T per key-tile kt (rows=key, cols=q); exp2; pack P[q][key] ----
#pragma unroll
    for (int kt = 0; kt < 2; ++kt) {
      f32x16 S;
#pragma unroll
      for (int r = 0; r < 16; ++r) S[r] = 0.f;
#pragma unroll
      for (int s = 0; s < 4; ++s) {
        short8 kf = *(const short8*)&Ks[(kt * 32 + q32) * 136 + h * 64 + s * 16 + hi * 8];
        S = MFMA32(kf, qf[s], S);  // A=K[key][d], B=Q[q][d] -> D=S^T[key][q]
      }
      float lh = 0.f;
#pragma unroll
      for (int rp = 0; rp < 8; ++rp) {
        float p0 = exp2f(S[2 * rp]), p1 = exp2f(S[2 * rp + 1]);
        lh += p0 + p1;
        // D rows r=2rp,2rp+1: key = 2*(rp&1) + 8*(rp>>1) + 4*hi (+1)
        *(unsigned*)&Pw[q32 * 72 + kt * 32 + (rp >> 1) * 8 + hi * 4 + (rp & 1) * 2] =
            pk2(p0, p1);
      }
      l += lh;
    }
    // ---- O^T += V^T x P ----
    short8 pf[4];
#pragma unroll
    for (int s = 0; s < 4; ++s)
      pf[s] = *(const short8*)&Pw[q32 * 72 + s * 16 + hi * 8];
    __builtin_amdgcn_s_setprio(1);
#pragma unroll
    for (int dt = 0; dt < 2; ++dt)
#pragma unroll
      for (int s = 0; s < 4; ++s) {
        short8 vf = *(const short8*)&Vs[(h * 64 + dt * 32 + q32) * 72 + s * 16 + hi * 8];
        o[dt] = MFMA32(vf, pf[s], o[dt]);  // A=V^T[d][key], B=P[q][key]
      }
    __builtin_amdgcn_s_setprio(0);
    __syncthreads();  // readers done before next commit (final iter: fences epi)
  }

  // ---- softmax denom (half-wave partner holds the other 16 key-rows) ----
  {
    float t = l;
    t += __shfl_xor(t, 32, 64);
    const float inv = 1.0f / t;
#pragma unroll
    for (int dt = 0; dt < 2; ++dt)
#pragma unroll
      for (int r = 0; r < 16; ++r) o[dt][r] *= inv;
  }

  // ---- epilogue: both h-waves of qt write O-halves into shared Ew[32][136],
  //      barrier, then split Wproj (wave h computes output cols h*64..h*64+63)
#pragma unroll
  for (int dt = 0; dt < 2; ++dt)
#pragma unroll
    for (int rp = 0; rp < 8; ++rp) {
      // D rows r=2rp,2rp+1 -> d = h*64 + dt*32 + 2*(rp&1) + 8*(rp>>1) + 4*hi
      *(unsigned*)&Ew[q32 * 136 + h * 64 + dt * 32 + (rp >> 1) * 8 + hi * 4 +
                      (rp & 1) * 2] = pk2(o[dt][2 * rp], o[dt][2 * rp + 1]);
    }
  __syncthreads();  // partner wave's O-half visible
#pragma unroll
  for (int mt = 0; mt < 2; ++mt) {
    short8 of[4];
#pragma unroll
    for (int kc = 0; kc < 4; ++kc)
      of[kc] = *(const short8*)&Ew[(mt * 16 + l16) * 136 + kc * 32 + quad * 8];
#pragma unroll
    for (int ntp = 0; ntp < 4; ++ntp) {
      const int nt = h * 4 + ntp;
      f32x4 pa = (f32x4){0.f, 0.f, 0.f, 0.f};
#pragma unroll
      for (int kc = 0; kc < 4; ++kc) {
        short8 w = *(const short8*)(WpT + (nt * 16 + l16) * 128 + kc * 32 + quad * 8);
        pa = MFMA16(of[kc], w, pa);  // A=O[q][d], B=Wp^T[c][d] -> D=[q][c]
      }
#pragma unroll
      for (int rr = 0; rr < 4; ++rr)
        out[(b * 16384 + row0 + wrow + mt * 16 + quad * 4 + rr) * 128 + nt * 16 + l16] =
            pa[rr];
    }
  }
}

// ---------------------------------------------------------------------------
extern "C" void kernel_launch(void* const* d_in, const int* in_sizes, int n_in,
                              void* d_out, int out_size, void* d_ws, size_t ws_size,
                              hipStream_t stream) {
  (void)in_sizes; (void)n_in; (void)out_size; (void)ws_size;
  const void* x = d_in[0];
  const void* Wq = d_in[1];
  const void* Wk = d_in[2];
  const void* Wv = d_in[3];
  const void* Wp = d_in[4];
  const void* srk = d_in[5];
  const void* sbias = d_in[6];
  const void* gamma = d_in[7];
  const void* beta = d_in[8];
  float* out = (float*)d_out;
  u16* ws = (u16*)d_ws;

  u16* WcT = ws;
  u16* WqT = ws + 262144;
  u16* WkT = ws + 278528;
  u16* WvT = ws + 294912;
  u16* WpT = ws + 311296;
  u16* Kb = ws + 327680;
  u16* Vt = ws + 851968;

  prep_kernel<<<dim3(1280), dim3(256), 0, stream>>>(srk, Wq, Wk, Wv, Wp, x, WcT);
  conv_ln_kv_kernel<<<dim3(256), dim3(1024), 16 * 16 * 128 * 4 + 16 * 136 * 2, stream>>>(
      x, WcT, sbias, gamma, beta, WkT, WvT, Kb, Vt);
  attn_kernel<<<dim3(512), dim3(512), (64 * 136 + 128 * 72 + 8 * 2304) * 2, stream>>>(
      x, WqT, WpT, Kb, Vt, out);
}